// Round 1
// baseline (364.473 us; speedup 1.0000x reference)
//
#include <hip/hip_runtime.h>
#include <hip/hip_fp16.h>

#define HW_ (512 * 512)

typedef _Float16 half_t;
typedef __attribute__((ext_vector_type(8))) _Float16 half8;

// ---------------------------------------------------------------------------
// Kernel A: transpose [C=32][512][512] fp32 planes -> [512][512][C=32] fp16
// ---------------------------------------------------------------------------
__global__ __launch_bounds__(256) void transpose_k(
    const float* __restrict__ xy, const float* __restrict__ xz,
    const float* __restrict__ yz, half_t* __restrict__ out)
{
    int b  = blockIdx.x;          // 3 * 512 * 8 blocks
    int xc = b & 7;               // x-chunk of 64
    int y  = (b >> 3) & 511;
    int p  = b >> 12;             // plane
    const float* __restrict__ src = (p == 0) ? xy : (p == 1) ? xz : yz;

    __shared__ half_t tile[32][68];   // pad to break bank conflicts
    int t = threadIdx.x;

#pragma unroll
    for (int i = 0; i < 8; ++i) {
        int e  = i * 256 + t;
        int c  = e >> 6;          // channel 0..31
        int xl = e & 63;          // x within chunk, coalesced along x
        tile[c][xl] = (half_t)src[(size_t)c * HW_ + y * 512 + xc * 64 + xl];
    }
    __syncthreads();

    half_t* __restrict__ dst = out + ((size_t)p * HW_ + y * 512 + xc * 64) * 32;
#pragma unroll
    for (int i = 0; i < 8; ++i) {
        int e  = i * 256 + t;
        int c  = e & 31;          // channel fastest -> contiguous 128B per wave
        int xl = e >> 5;
        dst[(size_t)xl * 32 + c] = tile[c][xl];
    }
}

// ---------------------------------------------------------------------------
// Bilinear helper (align_corners=True, border padding) — matches reference
// ---------------------------------------------------------------------------
__device__ __forceinline__ void corners(float gx, float gy,
                                        int& i00, int& i01, int& i10, int& i11,
                                        float& wnw, float& wne, float& wsw, float& wse)
{
    float ix = (gx + 1.f) * 0.5f * 511.f;
    float iy = (gy + 1.f) * 0.5f * 511.f;
    float fx = floorf(ix), fy = floorf(iy);
    float tx = ix - fx, ty = iy - fy;   // weights from UNclamped corner coords
    int x0 = (int)fx, y0 = (int)fy;
    int x1 = min(max(x0 + 1, 0), 511);
    int y1 = min(max(y0 + 1, 0), 511);
    x0 = min(max(x0, 0), 511);
    y0 = min(max(y0, 0), 511);
    i00 = y0 * 512 + x0;
    i01 = y0 * 512 + x1;
    i10 = y1 * 512 + x0;
    i11 = y1 * 512 + x1;
    wnw = (1.f - tx) * (1.f - ty);
    wne = tx * (1.f - ty);
    wsw = (1.f - tx) * ty;
    wse = tx * ty;
}

__device__ __forceinline__ void sample_tp(const half_t* __restrict__ pl,
                                          float gx, float gy, float* __restrict__ acc)
{
    int i00, i01, i10, i11;
    float wnw, wne, wsw, wse;
    corners(gx, gy, i00, i01, i10, i11, wnw, wne, wsw, wse);
    const half8* __restrict__ p00 = (const half8*)(pl + (size_t)i00 * 32);
    const half8* __restrict__ p01 = (const half8*)(pl + (size_t)i01 * 32);
    const half8* __restrict__ p10 = (const half8*)(pl + (size_t)i10 * 32);
    const half8* __restrict__ p11 = (const half8*)(pl + (size_t)i11 * 32);
#pragma unroll
    for (int v = 0; v < 4; ++v) {
        half8 a = p00[v], b = p01[v], c = p10[v], d = p11[v];
#pragma unroll
        for (int i = 0; i < 8; ++i) {
            acc[v * 8 + i] += wnw * (float)a[i] + wne * (float)b[i]
                            + wsw * (float)c[i] + wse * (float)d[i];
        }
    }
}

__device__ __forceinline__ void sample_dir(const float* __restrict__ pl,
                                           float gx, float gy, float* __restrict__ acc)
{
    int i00, i01, i10, i11;
    float wnw, wne, wsw, wse;
    corners(gx, gy, i00, i01, i10, i11, wnw, wne, wsw, wse);
#pragma unroll
    for (int c = 0; c < 32; ++c) {
        const float* __restrict__ b = pl + (size_t)c * HW_;
        acc[c] += wnw * b[i00] + wne * b[i01] + wsw * b[i10] + wse * b[i11];
    }
}

// ---------------------------------------------------------------------------
// Kernel B: fused sample + posenc + 4-layer MLP. One thread per pixel.
// Weights read via wave-uniform indices -> scalar loads (K$), no LDS needed.
// ---------------------------------------------------------------------------
template <bool TP>
__global__ __launch_bounds__(256) void decoder_k(
    const half_t* __restrict__ tp,
    const float* __restrict__ xy, const float* __restrict__ xz,
    const float* __restrict__ yz,
    const float* __restrict__ coords, const float* __restrict__ gauss,
    const float* __restrict__ W0, const float* __restrict__ b0,
    const float* __restrict__ W1, const float* __restrict__ b1,
    const float* __restrict__ W2, const float* __restrict__ b2,
    const float* __restrict__ W3, const float* __restrict__ b3,
    float* __restrict__ out)
{
    int pix = blockIdx.x * 256 + threadIdx.x;   // 1M pixels
    float cx = coords[(size_t)pix * 3 + 0];
    float cy = coords[(size_t)pix * 3 + 1];
    float cz = coords[(size_t)pix * 3 + 2];

    float act[64];
#pragma unroll
    for (int i = 0; i < 32; ++i) act[i] = 0.f;

    if (TP) {
        sample_tp(tp, cx, cy, act);
        sample_tp(tp + (size_t)HW_ * 32, cx, cz, act);
        sample_tp(tp + (size_t)2 * HW_ * 32, cy, cz, act);
    } else {
        sample_dir(xy, cx, cy, act);
        sample_dir(xz, cx, cz, act);
        sample_dir(yz, cy, cz, act);
    }
    const float inv3 = 1.f / 3.f;
#pragma unroll
    for (int i = 0; i < 32; ++i) act[i] *= inv3;

    // positional encoding: proj = (2*pi*coords) @ gauss[3][16]
    const float TWO_PI = 6.283185307179586f;
    float px = cx * TWO_PI, py = cy * TWO_PI, pz = cz * TWO_PI;
#pragma unroll
    for (int c = 0; c < 16; ++c) {
        float pr = px * gauss[c] + py * gauss[16 + c] + pz * gauss[32 + c];
        act[32 + c] = __sinf(pr);
        act[48 + c] = __cosf(pr);
    }

    float h[32];
    // ---- layer 0: 64 -> 32 ----
#pragma unroll
    for (int j = 0; j < 32; ++j) h[j] = b0[j];
#pragma unroll
    for (int k = 0; k < 64; ++k) {
        float a = act[k];
#pragma unroll
        for (int j = 0; j < 32; ++j) h[j] = fmaf(a, W0[k * 32 + j], h[j]);
    }
#pragma unroll
    for (int j = 0; j < 32; ++j) act[j] = h[j] >= 0.f ? h[j] : 0.01f * h[j];

    // ---- layer 1: 32 -> 32 ----
#pragma unroll
    for (int j = 0; j < 32; ++j) h[j] = b1[j];
#pragma unroll
    for (int k = 0; k < 32; ++k) {
        float a = act[k];
#pragma unroll
        for (int j = 0; j < 32; ++j) h[j] = fmaf(a, W1[k * 32 + j], h[j]);
    }
#pragma unroll
    for (int j = 0; j < 32; ++j) act[j] = h[j] >= 0.f ? h[j] : 0.01f * h[j];

    // ---- layer 2: 32 -> 32 ----
#pragma unroll
    for (int j = 0; j < 32; ++j) h[j] = b2[j];
#pragma unroll
    for (int k = 0; k < 32; ++k) {
        float a = act[k];
#pragma unroll
        for (int j = 0; j < 32; ++j) h[j] = fmaf(a, W2[k * 32 + j], h[j]);
    }
#pragma unroll
    for (int j = 0; j < 32; ++j) act[j] = h[j] >= 0.f ? h[j] : 0.01f * h[j];

    // ---- layer 3: 32 -> 4 ----
    float o[4];
#pragma unroll
    for (int j = 0; j < 4; ++j) o[j] = b3[j];
#pragma unroll
    for (int k = 0; k < 32; ++k) {
        float a = act[k];
#pragma unroll
        for (int j = 0; j < 4; ++j) o[j] = fmaf(a, W3[k * 4 + j], o[j]);
    }

    float4 ov = make_float4(o[0], o[1], o[2], o[3]);
    *(float4*)(out + (size_t)pix * 4) = ov;
}

// ---------------------------------------------------------------------------
extern "C" void kernel_launch(void* const* d_in, const int* in_sizes, int n_in,
                              void* d_out, int out_size, void* d_ws, size_t ws_size,
                              hipStream_t stream)
{
    const float* xy     = (const float*)d_in[0];
    const float* xz     = (const float*)d_in[1];
    const float* yz     = (const float*)d_in[2];
    const float* coords = (const float*)d_in[3];
    const float* gauss  = (const float*)d_in[4];
    const float* W0     = (const float*)d_in[5];
    const float* b0     = (const float*)d_in[6];
    const float* W1     = (const float*)d_in[7];
    const float* b1     = (const float*)d_in[8];
    const float* W2     = (const float*)d_in[9];
    const float* b2     = (const float*)d_in[10];
    const float* W3     = (const float*)d_in[11];
    const float* b3     = (const float*)d_in[12];
    float* out = (float*)d_out;

    const size_t need = (size_t)3 * HW_ * 32 * sizeof(half_t);  // 48 MB
    const int npix_blocks = (2048 * 512) / 256;                 // 4096

    if (ws_size >= need) {
        half_t* tp = (half_t*)d_ws;
        transpose_k<<<3 * 512 * 8, 256, 0, stream>>>(xy, xz, yz, tp);
        decoder_k<true><<<npix_blocks, 256, 0, stream>>>(
            tp, xy, xz, yz, coords, gauss,
            W0, b0, W1, b1, W2, b2, W3, b3, out);
    } else {
        decoder_k<false><<<npix_blocks, 256, 0, stream>>>(
            nullptr, xy, xz, yz, coords, gauss,
            W0, b0, W1, b1, W2, b2, W3, b3, out);
    }
}

// Round 2
// 338.705 us; speedup vs baseline: 1.0761x; 1.0761x over previous
//
#include <hip/hip_runtime.h>
#include <hip/hip_fp16.h>

#define HW_ (512 * 512)
#define NPIX (2048 * 512)
#define NBIN 4096

typedef _Float16 half_t;
typedef __attribute__((ext_vector_type(8))) _Float16 half8;

// ---------------------------------------------------------------------------
// Kernel A: transpose [C=32][512][512] fp32 planes -> [512][512][C=32] fp16
// ---------------------------------------------------------------------------
__global__ __launch_bounds__(256) void transpose_k(
    const float* __restrict__ xy, const float* __restrict__ xz,
    const float* __restrict__ yz, half_t* __restrict__ out)
{
    int b  = blockIdx.x;          // 3 * 512 * 8 blocks
    int xc = b & 7;               // x-chunk of 64
    int y  = (b >> 3) & 511;
    int p  = b >> 12;             // plane
    const float* __restrict__ src = (p == 0) ? xy : (p == 1) ? xz : yz;

    __shared__ half_t tile[32][68];   // pad to break bank conflicts
    int t = threadIdx.x;

#pragma unroll
    for (int i = 0; i < 8; ++i) {
        int e  = i * 256 + t;
        int c  = e >> 6;          // channel 0..31
        int xl = e & 63;          // x within chunk, coalesced along x
        tile[c][xl] = (half_t)src[(size_t)c * HW_ + y * 512 + xc * 64 + xl];
    }
    __syncthreads();

    half_t* __restrict__ dst = out + ((size_t)p * HW_ + y * 512 + xc * 64) * 32;
#pragma unroll
    for (int i = 0; i < 8; ++i) {
        int e  = i * 256 + t;
        int c  = e & 31;          // channel fastest -> contiguous 128B per wave
        int xl = e >> 5;
        dst[(size_t)xl * 32 + c] = tile[c][xl];
    }
}

// ---------------------------------------------------------------------------
// Morton binning (16x16x16 over [-1,1]^3)
// ---------------------------------------------------------------------------
__device__ __forceinline__ unsigned spread4(int v)
{
    return (v & 1) | ((v & 2) << 2) | ((v & 4) << 4) | ((v & 8) << 6);
}

__device__ __forceinline__ unsigned bin_of(float cx, float cy, float cz)
{
    int qx = min(max((int)((cx + 1.f) * 8.f), 0), 15);
    int qy = min(max((int)((cy + 1.f) * 8.f), 0), 15);
    int qz = min(max((int)((cz + 1.f) * 8.f), 0), 15);
    return spread4(qx) | (spread4(qy) << 1) | (spread4(qz) << 2);
}

__global__ void zero_hist_k(unsigned* __restrict__ h)
{
    h[blockIdx.x * 256 + threadIdx.x] = 0;
}

__global__ __launch_bounds__(256) void hist_k(const float* __restrict__ coords,
                                              unsigned* __restrict__ hist)
{
    int pix = blockIdx.x * 256 + threadIdx.x;
    float cx = coords[(size_t)pix * 3 + 0];
    float cy = coords[(size_t)pix * 3 + 1];
    float cz = coords[(size_t)pix * 3 + 2];
    atomicAdd(&hist[bin_of(cx, cy, cz)], 1u);
}

__global__ __launch_bounds__(256) void scan_k(const unsigned* __restrict__ hist,
                                              unsigned* __restrict__ ofs)
{
    __shared__ unsigned part[256];
    int t = threadIdx.x;
    unsigned loc[16], s = 0;
#pragma unroll
    for (int i = 0; i < 16; ++i) { loc[i] = s; s += hist[t * 16 + i]; }
    part[t] = s;
    __syncthreads();
    for (int d = 1; d < 256; d <<= 1) {
        unsigned v = (t >= d) ? part[t - d] : 0u;
        __syncthreads();
        part[t] += v;
        __syncthreads();
    }
    unsigned base = (t == 0) ? 0u : part[t - 1];
#pragma unroll
    for (int i = 0; i < 16; ++i) ofs[t * 16 + i] = base + loc[i];
}

__global__ __launch_bounds__(256) void scatter_k(const float* __restrict__ coords,
                                                 unsigned* __restrict__ ofs,
                                                 float4* __restrict__ sorted)
{
    int pix = blockIdx.x * 256 + threadIdx.x;
    float cx = coords[(size_t)pix * 3 + 0];
    float cy = coords[(size_t)pix * 3 + 1];
    float cz = coords[(size_t)pix * 3 + 2];
    unsigned pos = atomicAdd(&ofs[bin_of(cx, cy, cz)], 1u);
    sorted[pos] = make_float4(cx, cy, cz, __uint_as_float((unsigned)pix));
}

// ---------------------------------------------------------------------------
// Bilinear helper (align_corners=True, border padding) — matches reference
// ---------------------------------------------------------------------------
__device__ __forceinline__ void corners(float gx, float gy,
                                        int& i00, int& i01, int& i10, int& i11,
                                        float& wnw, float& wne, float& wsw, float& wse)
{
    float ix = (gx + 1.f) * 0.5f * 511.f;
    float iy = (gy + 1.f) * 0.5f * 511.f;
    float fx = floorf(ix), fy = floorf(iy);
    float tx = ix - fx, ty = iy - fy;   // weights from UNclamped corner coords
    int x0 = (int)fx, y0 = (int)fy;
    int x1 = min(max(x0 + 1, 0), 511);
    int y1 = min(max(y0 + 1, 0), 511);
    x0 = min(max(x0, 0), 511);
    y0 = min(max(y0, 0), 511);
    i00 = y0 * 512 + x0;
    i01 = y0 * 512 + x1;
    i10 = y1 * 512 + x0;
    i11 = y1 * 512 + x1;
    wnw = (1.f - tx) * (1.f - ty);
    wne = tx * (1.f - ty);
    wsw = (1.f - tx) * ty;
    wse = tx * ty;
}

__device__ __forceinline__ void sample_tp(const half_t* __restrict__ pl,
                                          float gx, float gy, float* __restrict__ acc)
{
    int i00, i01, i10, i11;
    float wnw, wne, wsw, wse;
    corners(gx, gy, i00, i01, i10, i11, wnw, wne, wsw, wse);
    const half8* __restrict__ p00 = (const half8*)(pl + (size_t)i00 * 32);
    const half8* __restrict__ p01 = (const half8*)(pl + (size_t)i01 * 32);
    const half8* __restrict__ p10 = (const half8*)(pl + (size_t)i10 * 32);
    const half8* __restrict__ p11 = (const half8*)(pl + (size_t)i11 * 32);
#pragma unroll
    for (int v = 0; v < 4; ++v) {
        half8 a = p00[v], b = p01[v], c = p10[v], d = p11[v];
#pragma unroll
        for (int i = 0; i < 8; ++i) {
            acc[v * 8 + i] += wnw * (float)a[i] + wne * (float)b[i]
                            + wsw * (float)c[i] + wse * (float)d[i];
        }
    }
}

__device__ __forceinline__ void sample_dir(const float* __restrict__ pl,
                                           float gx, float gy, float* __restrict__ acc)
{
    int i00, i01, i10, i11;
    float wnw, wne, wsw, wse;
    corners(gx, gy, i00, i01, i10, i11, wnw, wne, wsw, wse);
#pragma unroll
    for (int c = 0; c < 32; ++c) {
        const float* __restrict__ b = pl + (size_t)c * HW_;
        acc[c] += wnw * b[i00] + wne * b[i01] + wsw * b[i10] + wse * b[i11];
    }
}

// ---------------------------------------------------------------------------
// Shared decode body: sample + posenc + 4-layer MLP for one pixel.
// Weights read via wave-uniform indices -> scalar loads (K$), no LDS needed.
// ---------------------------------------------------------------------------
template <bool TP>
__device__ __forceinline__ void decode_px(
    const half_t* __restrict__ tp,
    const float* __restrict__ xy, const float* __restrict__ xz,
    const float* __restrict__ yz,
    float cx, float cy, float cz,
    const float* __restrict__ gauss,
    const float* __restrict__ W0, const float* __restrict__ b0,
    const float* __restrict__ W1, const float* __restrict__ b1,
    const float* __restrict__ W2, const float* __restrict__ b2,
    const float* __restrict__ W3, const float* __restrict__ b3,
    float* __restrict__ out, int pix)
{
    float act[64];
#pragma unroll
    for (int i = 0; i < 32; ++i) act[i] = 0.f;

    if (TP) {
        sample_tp(tp, cx, cy, act);
        sample_tp(tp + (size_t)HW_ * 32, cx, cz, act);
        sample_tp(tp + (size_t)2 * HW_ * 32, cy, cz, act);
    } else {
        sample_dir(xy, cx, cy, act);
        sample_dir(xz, cx, cz, act);
        sample_dir(yz, cy, cz, act);
    }
    const float inv3 = 1.f / 3.f;
#pragma unroll
    for (int i = 0; i < 32; ++i) act[i] *= inv3;

    const float TWO_PI = 6.283185307179586f;
    float px = cx * TWO_PI, py = cy * TWO_PI, pz = cz * TWO_PI;
#pragma unroll
    for (int c = 0; c < 16; ++c) {
        float pr = px * gauss[c] + py * gauss[16 + c] + pz * gauss[32 + c];
        act[32 + c] = __sinf(pr);
        act[48 + c] = __cosf(pr);
    }

    float h[32];
#pragma unroll
    for (int j = 0; j < 32; ++j) h[j] = b0[j];
#pragma unroll
    for (int k = 0; k < 64; ++k) {
        float a = act[k];
#pragma unroll
        for (int j = 0; j < 32; ++j) h[j] = fmaf(a, W0[k * 32 + j], h[j]);
    }
#pragma unroll
    for (int j = 0; j < 32; ++j) act[j] = h[j] >= 0.f ? h[j] : 0.01f * h[j];

#pragma unroll
    for (int j = 0; j < 32; ++j) h[j] = b1[j];
#pragma unroll
    for (int k = 0; k < 32; ++k) {
        float a = act[k];
#pragma unroll
        for (int j = 0; j < 32; ++j) h[j] = fmaf(a, W1[k * 32 + j], h[j]);
    }
#pragma unroll
    for (int j = 0; j < 32; ++j) act[j] = h[j] >= 0.f ? h[j] : 0.01f * h[j];

#pragma unroll
    for (int j = 0; j < 32; ++j) h[j] = b2[j];
#pragma unroll
    for (int k = 0; k < 32; ++k) {
        float a = act[k];
#pragma unroll
        for (int j = 0; j < 32; ++j) h[j] = fmaf(a, W2[k * 32 + j], h[j]);
    }
#pragma unroll
    for (int j = 0; j < 32; ++j) act[j] = h[j] >= 0.f ? h[j] : 0.01f * h[j];

    float o[4];
#pragma unroll
    for (int j = 0; j < 4; ++j) o[j] = b3[j];
#pragma unroll
    for (int k = 0; k < 32; ++k) {
        float a = act[k];
#pragma unroll
        for (int j = 0; j < 4; ++j) o[j] = fmaf(a, W3[k * 4 + j], o[j]);
    }

    *(float4*)(out + (size_t)pix * 4) = make_float4(o[0], o[1], o[2], o[3]);
}

// ---------------------------------------------------------------------------
// Kernel B (sorted): processes pixels in Morton-sorted order; XCD-chunked
// block swizzle keeps each XCD's plane windows L2-resident.
// ---------------------------------------------------------------------------
__global__ __launch_bounds__(256) void decoder_sorted_k(
    const half_t* __restrict__ tp, const float4* __restrict__ sorted,
    const float* __restrict__ gauss,
    const float* __restrict__ W0, const float* __restrict__ b0,
    const float* __restrict__ W1, const float* __restrict__ b1,
    const float* __restrict__ W2, const float* __restrict__ b2,
    const float* __restrict__ W3, const float* __restrict__ b3,
    float* __restrict__ out)
{
    // 4096 blocks; XCD x (= b%8 under round-robin dispatch) gets the
    // contiguous Morton range [x*512, (x+1)*512) of blocks.
    int b   = blockIdx.x;
    int swz = (b & 7) * 512 + (b >> 3);
    int j   = swz * 256 + threadIdx.x;

    float4 s = sorted[j];
    int pix  = (int)__float_as_uint(s.w);
    decode_px<true>(tp, nullptr, nullptr, nullptr, s.x, s.y, s.z,
                    gauss, W0, b0, W1, b1, W2, b2, W3, b3, out, pix);
}

// Fallback decoders (workspace too small for sort / transpose)
template <bool TP>
__global__ __launch_bounds__(256) void decoder_k(
    const half_t* __restrict__ tp,
    const float* __restrict__ xy, const float* __restrict__ xz,
    const float* __restrict__ yz,
    const float* __restrict__ coords, const float* __restrict__ gauss,
    const float* __restrict__ W0, const float* __restrict__ b0,
    const float* __restrict__ W1, const float* __restrict__ b1,
    const float* __restrict__ W2, const float* __restrict__ b2,
    const float* __restrict__ W3, const float* __restrict__ b3,
    float* __restrict__ out)
{
    int pix = blockIdx.x * 256 + threadIdx.x;
    float cx = coords[(size_t)pix * 3 + 0];
    float cy = coords[(size_t)pix * 3 + 1];
    float cz = coords[(size_t)pix * 3 + 2];
    decode_px<TP>(tp, xy, xz, yz, cx, cy, cz,
                  gauss, W0, b0, W1, b1, W2, b2, W3, b3, out, pix);
}

// ---------------------------------------------------------------------------
extern "C" void kernel_launch(void* const* d_in, const int* in_sizes, int n_in,
                              void* d_out, int out_size, void* d_ws, size_t ws_size,
                              hipStream_t stream)
{
    const float* xy     = (const float*)d_in[0];
    const float* xz     = (const float*)d_in[1];
    const float* yz     = (const float*)d_in[2];
    const float* coords = (const float*)d_in[3];
    const float* gauss  = (const float*)d_in[4];
    const float* W0     = (const float*)d_in[5];
    const float* b0     = (const float*)d_in[6];
    const float* W1     = (const float*)d_in[7];
    const float* b1     = (const float*)d_in[8];
    const float* W2     = (const float*)d_in[9];
    const float* b2     = (const float*)d_in[10];
    const float* W3     = (const float*)d_in[11];
    const float* b3     = (const float*)d_in[12];
    float* out = (float*)d_out;

    const size_t plane_bytes = (size_t)3 * HW_ * 32 * sizeof(half_t);       // 48 MB
    const size_t hist_off    = plane_bytes;                                  // 16 KB
    const size_t ofs_off     = hist_off + NBIN * sizeof(unsigned);
    const size_t sorted_off  = ofs_off + NBIN * sizeof(unsigned);
    const size_t need_sorted = sorted_off + (size_t)NPIX * sizeof(float4);   // ~64 MB
    const int npix_blocks    = NPIX / 256;                                   // 4096

    if (ws_size >= need_sorted) {
        half_t*   tp     = (half_t*)d_ws;
        unsigned* hist   = (unsigned*)((char*)d_ws + hist_off);
        unsigned* ofs    = (unsigned*)((char*)d_ws + ofs_off);
        float4*   sorted = (float4*)((char*)d_ws + sorted_off);

        transpose_k<<<3 * 512 * 8, 256, 0, stream>>>(xy, xz, yz, tp);
        zero_hist_k<<<NBIN / 256, 256, 0, stream>>>(hist);
        hist_k<<<npix_blocks, 256, 0, stream>>>(coords, hist);
        scan_k<<<1, 256, 0, stream>>>(hist, ofs);
        scatter_k<<<npix_blocks, 256, 0, stream>>>(coords, ofs, sorted);
        decoder_sorted_k<<<npix_blocks, 256, 0, stream>>>(
            tp, sorted, gauss, W0, b0, W1, b1, W2, b2, W3, b3, out);
    } else if (ws_size >= plane_bytes) {
        half_t* tp = (half_t*)d_ws;
        transpose_k<<<3 * 512 * 8, 256, 0, stream>>>(xy, xz, yz, tp);
        decoder_k<true><<<npix_blocks, 256, 0, stream>>>(
            tp, xy, xz, yz, coords, gauss,
            W0, b0, W1, b1, W2, b2, W3, b3, out);
    } else {
        decoder_k<false><<<npix_blocks, 256, 0, stream>>>(
            nullptr, xy, xz, yz, coords, gauss,
            W0, b0, W1, b1, W2, b2, W3, b3, out);
    }
}

// Round 3
// 225.908 us; speedup vs baseline: 1.6134x; 1.4993x over previous
//
#include <hip/hip_runtime.h>
#include <hip/hip_fp16.h>

#define HW_ (512 * 512)
#define NPIX (2048 * 512)
#define NBIN 512            // 8x8x8 Morton bins
#define SORT_BLOCKS 256
#define PXPT 16             // pixels per thread in sort kernels (256*256*16 = 1M)

typedef _Float16 half_t;
typedef __attribute__((ext_vector_type(8))) _Float16 half8;
typedef __attribute__((ext_vector_type(2))) _Float16 half2v;
typedef unsigned int uint;

// ---------------------------------------------------------------------------
// helpers
// ---------------------------------------------------------------------------
__device__ __forceinline__ half8 splat8(float w)
{
    half_t h = (half_t)w;
    half8 r = {h, h, h, h, h, h, h, h};
    return r;
}

__device__ __forceinline__ half2v pair2(half8 v, int p)  // p static after unroll
{
    half2v r = {v[2 * p], v[2 * p + 1]};
    return r;
}

__device__ __forceinline__ half2v as_h2(uint u)
{
    return __builtin_bit_cast(half2v, u);
}

__device__ __forceinline__ float fdot2f(half2v a, half2v b, float c)
{
    return __builtin_amdgcn_fdot2(a, b, c, false);
}

__device__ __forceinline__ uint packh(float lo, float hi)
{
    half_t l = (half_t)lo, h = (half_t)hi;
    unsigned short lb = __builtin_bit_cast(unsigned short, l);
    unsigned short hb = __builtin_bit_cast(unsigned short, h);
    return (uint)lb | ((uint)hb << 16);
}

// ---------------------------------------------------------------------------
// Kernel A: transpose [C=32][512][512] fp32 planes -> [512][512][C=32] fp16
// ---------------------------------------------------------------------------
__global__ __launch_bounds__(256) void transpose_k(
    const float* __restrict__ xy, const float* __restrict__ xz,
    const float* __restrict__ yz, half_t* __restrict__ out)
{
    int b  = blockIdx.x;          // 3 * 512 * 8 blocks
    int xc = b & 7;               // x-chunk of 64
    int y  = (b >> 3) & 511;
    int p  = b >> 12;             // plane
    const float* __restrict__ src = (p == 0) ? xy : (p == 1) ? xz : yz;

    __shared__ half_t tile[32][68];
    int t = threadIdx.x;

#pragma unroll
    for (int i = 0; i < 8; ++i) {
        int e  = i * 256 + t;
        int c  = e >> 6;
        int xl = e & 63;
        tile[c][xl] = (half_t)src[(size_t)c * HW_ + y * 512 + xc * 64 + xl];
    }
    __syncthreads();

    half_t* __restrict__ dst = out + ((size_t)p * HW_ + y * 512 + xc * 64) * 32;
#pragma unroll
    for (int i = 0; i < 8; ++i) {
        int e  = i * 256 + t;
        int c  = e & 31;
        int xl = e >> 5;
        dst[(size_t)xl * 32 + c] = tile[c][xl];
    }
}

// ---------------------------------------------------------------------------
// Weight prep: pack fp32 weights into fp16 k-pair half2 words.
// Layout in wp: [0,1024) L0 (kk*32+j, 1/3 folded into kk<16 rows),
//               [1024,1536) L1, [1536,2048) L2, [2048,2112) L3 (kk*4+j)
// ---------------------------------------------------------------------------
__global__ void prep_w_k(const float* __restrict__ W0, const float* __restrict__ W1,
                         const float* __restrict__ W2, const float* __restrict__ W3,
                         uint* __restrict__ wp)
{
    int t = blockIdx.x * 256 + threadIdx.x;
    if (t < 1024) {
        int kk = t >> 5, j = t & 31;
        float s = (kk < 16) ? (1.f / 3.f) : 1.f;
        wp[t] = packh(W0[(2 * kk) * 32 + j] * s, W0[(2 * kk + 1) * 32 + j] * s);
    } else if (t < 1536) {
        int u = t - 1024; int kk = u >> 5, j = u & 31;
        wp[t] = packh(W1[(2 * kk) * 32 + j], W1[(2 * kk + 1) * 32 + j]);
    } else if (t < 2048) {
        int u = t - 1536; int kk = u >> 5, j = u & 31;
        wp[t] = packh(W2[(2 * kk) * 32 + j], W2[(2 * kk + 1) * 32 + j]);
    } else if (t < 2112) {
        int u = t - 2048; int kk = u >> 2, j = u & 3;
        wp[t] = packh(W3[(2 * kk) * 4 + j], W3[(2 * kk + 1) * 4 + j]);
    }
}

// ---------------------------------------------------------------------------
// Morton binning (8x8x8 over [-1,1]^3)
// ---------------------------------------------------------------------------
__device__ __forceinline__ unsigned spread3(int v)
{
    return (v & 1) | ((v & 2) << 1) | ((v & 4) << 2);
}

__device__ __forceinline__ unsigned bin_of(float cx, float cy, float cz)
{
    int qx = min(max((int)((cx + 1.f) * 4.f), 0), 7);
    int qy = min(max((int)((cy + 1.f) * 4.f), 0), 7);
    int qz = min(max((int)((cz + 1.f) * 4.f), 0), 7);
    return spread3(qx) | (spread3(qy) << 1) | (spread3(qz) << 2);
}

__global__ void zero_hist_k(unsigned* __restrict__ h)
{
    h[threadIdx.x + blockIdx.x * 256] = 0;
}

// LDS-aggregated histogram: 262K global atomics instead of 1M
__global__ __launch_bounds__(256) void hist_k(const float* __restrict__ coords,
                                              unsigned* __restrict__ hist)
{
    __shared__ unsigned lcnt[NBIN];
    int t = threadIdx.x;
    lcnt[t] = 0; lcnt[t + 256] = 0;
    __syncthreads();
    int base = blockIdx.x * (PXPT * 256);
#pragma unroll
    for (int i = 0; i < PXPT; ++i) {
        int px = base + i * 256 + t;
        float cx = coords[(size_t)px * 3 + 0];
        float cy = coords[(size_t)px * 3 + 1];
        float cz = coords[(size_t)px * 3 + 2];
        atomicAdd(&lcnt[bin_of(cx, cy, cz)], 1u);
    }
    __syncthreads();
    if (lcnt[t])       atomicAdd(&hist[t],       lcnt[t]);
    if (lcnt[t + 256]) atomicAdd(&hist[t + 256], lcnt[t + 256]);
}

__global__ __launch_bounds__(256) void scan_k(const unsigned* __restrict__ hist,
                                              unsigned* __restrict__ ofs)
{
    __shared__ unsigned part[256];
    int t = threadIdx.x;
    unsigned s0 = hist[2 * t], s1 = hist[2 * t + 1];
    part[t] = s0 + s1;
    __syncthreads();
    for (int d = 1; d < 256; d <<= 1) {
        unsigned v = (t >= d) ? part[t - d] : 0u;
        __syncthreads();
        part[t] += v;
        __syncthreads();
    }
    unsigned base = (t == 0) ? 0u : part[t - 1];
    ofs[2 * t]     = base;
    ofs[2 * t + 1] = base + s0;
}

// Rank via LDS atomics + one global reservation per (block,bin)
__global__ __launch_bounds__(256) void scatter_k(const float* __restrict__ coords,
                                                 unsigned* __restrict__ ofs,
                                                 float4* __restrict__ sorted)
{
    __shared__ unsigned lcnt[NBIN];
    __shared__ unsigned lbase[NBIN];
    int t = threadIdx.x;
    lcnt[t] = 0; lcnt[t + 256] = 0;
    __syncthreads();

    int base = blockIdx.x * (PXPT * 256);
    uint sav[PXPT];
#pragma unroll
    for (int i = 0; i < PXPT; ++i) {
        int px = base + i * 256 + t;
        float cx = coords[(size_t)px * 3 + 0];
        float cy = coords[(size_t)px * 3 + 1];
        float cz = coords[(size_t)px * 3 + 2];
        unsigned b = bin_of(cx, cy, cz);
        unsigned r = atomicAdd(&lcnt[b], 1u);
        sav[i] = (b << 16) | r;          // r < 4096 fits
    }
    __syncthreads();
    lbase[t]       = lcnt[t]       ? atomicAdd(&ofs[t],       lcnt[t])       : 0u;
    lbase[t + 256] = lcnt[t + 256] ? atomicAdd(&ofs[t + 256], lcnt[t + 256]) : 0u;
    __syncthreads();

#pragma unroll
    for (int i = 0; i < PXPT; ++i) {
        int px = base + i * 256 + t;
        float cx = coords[(size_t)px * 3 + 0];
        float cy = coords[(size_t)px * 3 + 1];
        float cz = coords[(size_t)px * 3 + 2];
        unsigned b = sav[i] >> 16, r = sav[i] & 0xffffu;
        sorted[lbase[b] + r] = make_float4(cx, cy, cz, __uint_as_float((uint)px));
    }
}

// ---------------------------------------------------------------------------
// Bilinear corner math (align_corners=True, border padding)
// ---------------------------------------------------------------------------
__device__ __forceinline__ void corners(float gx, float gy,
                                        int& i00, int& i01, int& i10, int& i11,
                                        float& wnw, float& wne, float& wsw, float& wse)
{
    float ix = (gx + 1.f) * 0.5f * 511.f;
    float iy = (gy + 1.f) * 0.5f * 511.f;
    float fx = floorf(ix), fy = floorf(iy);
    float tx = ix - fx, ty = iy - fy;
    int x0 = (int)fx, y0 = (int)fy;
    int x1 = min(max(x0 + 1, 0), 511);
    int y1 = min(max(y0 + 1, 0), 511);
    x0 = min(max(x0, 0), 511);
    y0 = min(max(y0, 0), 511);
    i00 = y0 * 512 + x0;
    i01 = y0 * 512 + x1;
    i10 = y1 * 512 + x0;
    i11 = y1 * 512 + x1;
    wnw = (1.f - tx) * (1.f - ty);
    wne = tx * (1.f - ty);
    wsw = (1.f - tx) * ty;
    wse = tx * ty;
}

// packed-fp16 bilinear accumulate (16 v_pk_fma per plane)
__device__ __forceinline__ void sample_tp_h(const half_t* __restrict__ pl,
                                            float gx, float gy, half8* __restrict__ acc)
{
    int i00, i01, i10, i11;
    float wnw, wne, wsw, wse;
    corners(gx, gy, i00, i01, i10, i11, wnw, wne, wsw, wse);
    const half8* __restrict__ p00 = (const half8*)(pl + (size_t)i00 * 32);
    const half8* __restrict__ p01 = (const half8*)(pl + (size_t)i01 * 32);
    const half8* __restrict__ p10 = (const half8*)(pl + (size_t)i10 * 32);
    const half8* __restrict__ p11 = (const half8*)(pl + (size_t)i11 * 32);
    half8 W00 = splat8(wnw), W01 = splat8(wne), W10 = splat8(wsw), W11 = splat8(wse);
#pragma unroll
    for (int v = 0; v < 4; ++v) {
        half8 a = p00[v], b = p01[v], c = p10[v], d = p11[v];
        acc[v] = acc[v] + a * W00 + b * W01 + c * W10 + d * W11;
    }
}

// ---------------------------------------------------------------------------
// Main decoder: sorted order, packed-fp16 sampling, dot2 MLP
// ---------------------------------------------------------------------------
__global__ __launch_bounds__(256) void decoder_sorted_k(
    const half_t* __restrict__ tp, const float4* __restrict__ sorted,
    const float* __restrict__ gauss, const uint* __restrict__ wp,
    const float* __restrict__ b0, const float* __restrict__ b1,
    const float* __restrict__ b2, const float* __restrict__ b3,
    float* __restrict__ out)
{
    int b   = blockIdx.x;
    int swz = (b & 7) * 512 + (b >> 3);   // XCD-chunked: each XCD walks a contiguous Morton range
    int j   = swz * 256 + threadIdx.x;

    float4 s = sorted[j];
    int pix  = (int)__float_as_uint(s.w);
    float cx = s.x, cy = s.y, cz = s.z;

    // --- triplanar sample (sum of 3 planes; /3 folded into W0) ---
    half8 acc[4] = {};
    sample_tp_h(tp,                       cx, cy, acc);
    sample_tp_h(tp + (size_t)HW_ * 32,    cx, cz, acc);
    sample_tp_h(tp + (size_t)2 * HW_ * 32, cy, cz, acc);

    // --- positional encoding, packed into k-pairs ---
    const float TWO_PI = 6.283185307179586f;
    float px = cx * TWO_PI, py = cy * TWO_PI, pz = cz * TWO_PI;
    float sn[16], cs[16];
#pragma unroll
    for (int c = 0; c < 16; ++c) {
        float pr = px * gauss[c] + py * gauss[16 + c] + pz * gauss[32 + c];
        sn[c] = __sinf(pr);
        cs[c] = __cosf(pr);
    }
    half2v sp[8], cp[8];
#pragma unroll
    for (int m = 0; m < 8; ++m) {
        sp[m] = half2v{(half_t)sn[2 * m], (half_t)sn[2 * m + 1]};
        cp[m] = half2v{(half_t)cs[2 * m], (half_t)cs[2 * m + 1]};
    }

    const uint* __restrict__ w0p = wp;
    const uint* __restrict__ w1p = wp + 1024;
    const uint* __restrict__ w2p = wp + 1536;
    const uint* __restrict__ w3p = wp + 2048;

    float h[32];
    // ---- layer 0: 64 -> 32 (dot2) ----
#pragma unroll
    for (int jj = 0; jj < 32; ++jj) h[jj] = b0[jj];
#pragma unroll
    for (int kk = 0; kk < 16; ++kk) {
        half2v a = pair2(acc[kk >> 2], kk & 3);
#pragma unroll
        for (int jj = 0; jj < 32; ++jj) h[jj] = fdot2f(a, as_h2(w0p[kk * 32 + jj]), h[jj]);
    }
#pragma unroll
    for (int m = 0; m < 8; ++m) {
        half2v a = sp[m];
#pragma unroll
        for (int jj = 0; jj < 32; ++jj) h[jj] = fdot2f(a, as_h2(w0p[(16 + m) * 32 + jj]), h[jj]);
    }
#pragma unroll
    for (int m = 0; m < 8; ++m) {
        half2v a = cp[m];
#pragma unroll
        for (int jj = 0; jj < 32; ++jj) h[jj] = fdot2f(a, as_h2(w0p[(24 + m) * 32 + jj]), h[jj]);
    }

    half2v xp[16];
    // ---- layer 1 ----
#pragma unroll
    for (int m = 0; m < 16; ++m) {
        float v0 = h[2 * m],     l0 = v0 >= 0.f ? v0 : 0.01f * v0;
        float v1 = h[2 * m + 1], l1 = v1 >= 0.f ? v1 : 0.01f * v1;
        xp[m] = half2v{(half_t)l0, (half_t)l1};
    }
#pragma unroll
    for (int jj = 0; jj < 32; ++jj) h[jj] = b1[jj];
#pragma unroll
    for (int kk = 0; kk < 16; ++kk) {
        half2v a = xp[kk];
#pragma unroll
        for (int jj = 0; jj < 32; ++jj) h[jj] = fdot2f(a, as_h2(w1p[kk * 32 + jj]), h[jj]);
    }

    // ---- layer 2 ----
#pragma unroll
    for (int m = 0; m < 16; ++m) {
        float v0 = h[2 * m],     l0 = v0 >= 0.f ? v0 : 0.01f * v0;
        float v1 = h[2 * m + 1], l1 = v1 >= 0.f ? v1 : 0.01f * v1;
        xp[m] = half2v{(half_t)l0, (half_t)l1};
    }
#pragma unroll
    for (int jj = 0; jj < 32; ++jj) h[jj] = b2[jj];
#pragma unroll
    for (int kk = 0; kk < 16; ++kk) {
        half2v a = xp[kk];
#pragma unroll
        for (int jj = 0; jj < 32; ++jj) h[jj] = fdot2f(a, as_h2(w2p[kk * 32 + jj]), h[jj]);
    }

    // ---- layer 3: 32 -> 4 ----
#pragma unroll
    for (int m = 0; m < 16; ++m) {
        float v0 = h[2 * m],     l0 = v0 >= 0.f ? v0 : 0.01f * v0;
        float v1 = h[2 * m + 1], l1 = v1 >= 0.f ? v1 : 0.01f * v1;
        xp[m] = half2v{(half_t)l0, (half_t)l1};
    }
    float o[4];
#pragma unroll
    for (int jj = 0; jj < 4; ++jj) o[jj] = b3[jj];
#pragma unroll
    for (int kk = 0; kk < 16; ++kk) {
        half2v a = xp[kk];
#pragma unroll
        for (int jj = 0; jj < 4; ++jj) o[jj] = fdot2f(a, as_h2(w3p[kk * 4 + jj]), o[jj]);
    }

    *(float4*)(out + (size_t)pix * 4) = make_float4(o[0], o[1], o[2], o[3]);
}

// ---------------------------------------------------------------------------
// Fallback scalar decoder (small workspace) — correctness path only
// ---------------------------------------------------------------------------
__device__ __forceinline__ void sample_dir(const float* __restrict__ pl,
                                           float gx, float gy, float* __restrict__ acc)
{
    int i00, i01, i10, i11;
    float wnw, wne, wsw, wse;
    corners(gx, gy, i00, i01, i10, i11, wnw, wne, wsw, wse);
#pragma unroll
    for (int c = 0; c < 32; ++c) {
        const float* __restrict__ b = pl + (size_t)c * HW_;
        acc[c] += wnw * b[i00] + wne * b[i01] + wsw * b[i10] + wse * b[i11];
    }
}

__global__ __launch_bounds__(256) void decoder_fb_k(
    const float* __restrict__ xy, const float* __restrict__ xz,
    const float* __restrict__ yz,
    const float* __restrict__ coords, const float* __restrict__ gauss,
    const float* __restrict__ W0, const float* __restrict__ b0,
    const float* __restrict__ W1, const float* __restrict__ b1,
    const float* __restrict__ W2, const float* __restrict__ b2,
    const float* __restrict__ W3, const float* __restrict__ b3,
    float* __restrict__ out)
{
    int pix = blockIdx.x * 256 + threadIdx.x;
    float cx = coords[(size_t)pix * 3 + 0];
    float cy = coords[(size_t)pix * 3 + 1];
    float cz = coords[(size_t)pix * 3 + 2];

    float act[64];
#pragma unroll
    for (int i = 0; i < 32; ++i) act[i] = 0.f;
    sample_dir(xy, cx, cy, act);
    sample_dir(xz, cx, cz, act);
    sample_dir(yz, cy, cz, act);
#pragma unroll
    for (int i = 0; i < 32; ++i) act[i] *= (1.f / 3.f);

    const float TWO_PI = 6.283185307179586f;
    float px = cx * TWO_PI, py = cy * TWO_PI, pz = cz * TWO_PI;
#pragma unroll
    for (int c = 0; c < 16; ++c) {
        float pr = px * gauss[c] + py * gauss[16 + c] + pz * gauss[32 + c];
        act[32 + c] = __sinf(pr);
        act[48 + c] = __cosf(pr);
    }

    float h[32];
#pragma unroll
    for (int jj = 0; jj < 32; ++jj) h[jj] = b0[jj];
#pragma unroll
    for (int k = 0; k < 64; ++k) {
        float a = act[k];
#pragma unroll
        for (int jj = 0; jj < 32; ++jj) h[jj] = fmaf(a, W0[k * 32 + jj], h[jj]);
    }
#pragma unroll
    for (int jj = 0; jj < 32; ++jj) act[jj] = h[jj] >= 0.f ? h[jj] : 0.01f * h[jj];
#pragma unroll
    for (int jj = 0; jj < 32; ++jj) h[jj] = b1[jj];
#pragma unroll
    for (int k = 0; k < 32; ++k) {
        float a = act[k];
#pragma unroll
        for (int jj = 0; jj < 32; ++jj) h[jj] = fmaf(a, W1[k * 32 + jj], h[jj]);
    }
#pragma unroll
    for (int jj = 0; jj < 32; ++jj) act[jj] = h[jj] >= 0.f ? h[jj] : 0.01f * h[jj];
#pragma unroll
    for (int jj = 0; jj < 32; ++jj) h[jj] = b2[jj];
#pragma unroll
    for (int k = 0; k < 32; ++k) {
        float a = act[k];
#pragma unroll
        for (int jj = 0; jj < 32; ++jj) h[jj] = fmaf(a, W2[k * 32 + jj], h[jj]);
    }
#pragma unroll
    for (int jj = 0; jj < 32; ++jj) act[jj] = h[jj] >= 0.f ? h[jj] : 0.01f * h[jj];
    float o[4];
#pragma unroll
    for (int jj = 0; jj < 4; ++jj) o[jj] = b3[jj];
#pragma unroll
    for (int k = 0; k < 32; ++k) {
        float a = act[k];
#pragma unroll
        for (int jj = 0; jj < 4; ++jj) o[jj] = fmaf(a, W3[k * 4 + jj], o[jj]);
    }
    *(float4*)(out + (size_t)pix * 4) = make_float4(o[0], o[1], o[2], o[3]);
}

// ---------------------------------------------------------------------------
extern "C" void kernel_launch(void* const* d_in, const int* in_sizes, int n_in,
                              void* d_out, int out_size, void* d_ws, size_t ws_size,
                              hipStream_t stream)
{
    const float* xy     = (const float*)d_in[0];
    const float* xz     = (const float*)d_in[1];
    const float* yz     = (const float*)d_in[2];
    const float* coords = (const float*)d_in[3];
    const float* gauss  = (const float*)d_in[4];
    const float* W0     = (const float*)d_in[5];
    const float* b0     = (const float*)d_in[6];
    const float* W1     = (const float*)d_in[7];
    const float* b1     = (const float*)d_in[8];
    const float* W2     = (const float*)d_in[9];
    const float* b2     = (const float*)d_in[10];
    const float* W3     = (const float*)d_in[11];
    const float* b3     = (const float*)d_in[12];
    float* out = (float*)d_out;

    const size_t plane_bytes = (size_t)3 * HW_ * 32 * sizeof(half_t);       // 48 MB
    const size_t hist_off    = plane_bytes;
    const size_t ofs_off     = hist_off + 4096;                              // NBIN*4 padded
    const size_t wp_off      = ofs_off + 4096;
    const size_t sorted_off  = wp_off + 16384;                               // 2112*4 padded
    const size_t need_sorted = sorted_off + (size_t)NPIX * sizeof(float4);
    const int npix_blocks    = NPIX / 256;                                   // 4096

    if (ws_size >= need_sorted) {
        half_t*   tp     = (half_t*)d_ws;
        unsigned* hist   = (unsigned*)((char*)d_ws + hist_off);
        unsigned* ofs    = (unsigned*)((char*)d_ws + ofs_off);
        uint*     wp     = (uint*)((char*)d_ws + wp_off);
        float4*   sorted = (float4*)((char*)d_ws + sorted_off);

        transpose_k<<<3 * 512 * 8, 256, 0, stream>>>(xy, xz, yz, tp);
        prep_w_k<<<9, 256, 0, stream>>>(W0, W1, W2, W3, wp);
        zero_hist_k<<<NBIN / 256, 256, 0, stream>>>(hist);
        hist_k<<<SORT_BLOCKS, 256, 0, stream>>>(coords, hist);
        scan_k<<<1, 256, 0, stream>>>(hist, ofs);
        scatter_k<<<SORT_BLOCKS, 256, 0, stream>>>(coords, ofs, sorted);
        decoder_sorted_k<<<npix_blocks, 256, 0, stream>>>(
            tp, sorted, gauss, wp, b0, b1, b2, b3, out);
    } else {
        decoder_fb_k<<<npix_blocks, 256, 0, stream>>>(
            xy, xz, yz, coords, gauss,
            W0, b0, W1, b1, W2, b2, W3, b3, out);
    }
}

// Round 5
// 189.973 us; speedup vs baseline: 1.9186x; 1.1892x over previous
//
#include <hip/hip_runtime.h>
#include <hip/hip_fp16.h>

#define HW_ (512 * 512)
#define NPIX (2048 * 512)
#define NBIN 4096           // 16x16x16 Morton bins
#define SORT_BLOCKS 256
#define PXPT 16             // pixels per thread in sort kernels

typedef _Float16 half_t;
typedef __attribute__((ext_vector_type(8))) _Float16 half8;
typedef __attribute__((ext_vector_type(4))) float f32x4;
typedef unsigned int uint;

__device__ __forceinline__ half8 splat8(float w)
{
    half_t h = (half_t)w;
    half8 r = {h, h, h, h, h, h, h, h};
    return r;
}

__device__ __forceinline__ uint packh(float lo, float hi)
{
    half_t l = (half_t)lo, h = (half_t)hi;
    unsigned short lb = __builtin_bit_cast(unsigned short, l);
    unsigned short hb = __builtin_bit_cast(unsigned short, h);
    return (uint)lb | ((uint)hb << 16);
}

// pack two fp32 -> one u32 of 2 fp16 (RTZ) via HW instruction
__device__ __forceinline__ uint pkrtz_u32(float lo, float hi)
{
    return __builtin_bit_cast(uint, __builtin_amdgcn_cvt_pkrtz(lo, hi));
}

// ---------------------------------------------------------------------------
// Morton binning (16x16x16)
// ---------------------------------------------------------------------------
__device__ __forceinline__ unsigned spread4(int v)
{
    return (v & 1) | ((v & 2) << 2) | ((v & 4) << 4) | ((v & 8) << 6);
}

__device__ __forceinline__ unsigned bin_of(float cx, float cy, float cz)
{
    int qx = min(max((int)((cx + 1.f) * 8.f), 0), 15);
    int qy = min(max((int)((cy + 1.f) * 8.f), 0), 15);
    int qz = min(max((int)((cz + 1.f) * 8.f), 0), 15);
    return spread4(qx) | (spread4(qy) << 1) | (spread4(qz) << 2);
}

// ---------------------------------------------------------------------------
// Kernel 1 (merged): transpose planes -> fp16 [H][W][C]  ||  LDS histogram
//                    || weight-fragment prep
// ---------------------------------------------------------------------------
__global__ __launch_bounds__(256) void k1_merged(
    const float* __restrict__ xy, const float* __restrict__ xz,
    const float* __restrict__ yz, half_t* __restrict__ tp,
    const float* __restrict__ coords, unsigned* __restrict__ hist,
    const float* __restrict__ W0, const float* __restrict__ W1,
    const float* __restrict__ W2, const float* __restrict__ W3,
    const float* __restrict__ b0, const float* __restrict__ b1,
    const float* __restrict__ b2, const float* __restrict__ b3,
    uint* __restrict__ wfrag, float* __restrict__ bb)
{
    __shared__ __align__(16) uint sh[4096];   // 16 KB: tile or lcnt
    int b = blockIdx.x;
    int t = threadIdx.x;

    if (b < 12288) {
        // ---- transpose ----
        half_t (*tile)[68] = (half_t(*)[68])sh;
        int xc = b & 7;
        int y  = (b >> 3) & 511;
        int p  = b >> 12;
        const float* __restrict__ src = (p == 0) ? xy : (p == 1) ? xz : yz;
#pragma unroll
        for (int i = 0; i < 8; ++i) {
            int e  = i * 256 + t;
            int c  = e >> 6;
            int xl = e & 63;
            tile[c][xl] = (half_t)src[(size_t)c * HW_ + y * 512 + xc * 64 + xl];
        }
        __syncthreads();
        half_t* __restrict__ dst = tp + ((size_t)p * HW_ + y * 512 + xc * 64) * 32;
#pragma unroll
        for (int i = 0; i < 8; ++i) {
            int e  = i * 256 + t;
            int c  = e & 31;
            int xl = e >> 5;
            dst[(size_t)xl * 32 + c] = tile[c][xl];
        }
    } else if (b < 12288 + SORT_BLOCKS) {
        // ---- histogram (LDS-aggregated) ----
        uint* lcnt = sh;
#pragma unroll
        for (int i = 0; i < NBIN / 256; ++i) lcnt[i * 256 + t] = 0;
        __syncthreads();
        int base = (b - 12288) * (PXPT * 256);
#pragma unroll
        for (int i = 0; i < PXPT; ++i) {
            int px = base + i * 256 + t;
            float cx = coords[(size_t)px * 3 + 0];
            float cy = coords[(size_t)px * 3 + 1];
            float cz = coords[(size_t)px * 3 + 2];
            atomicAdd(&lcnt[bin_of(cx, cy, cz)], 1u);
        }
        __syncthreads();
#pragma unroll
        for (int i = 0; i < NBIN / 256; ++i) {
            uint v = lcnt[i * 256 + t];
            if (v) atomicAdd(&hist[i * 256 + t], v);
        }
    } else {
        // ---- weight fragment prep ----
        int tid = (b - 12288 - SORT_BLOCKS) * 256 + t;
        if (tid < 2304) {
            int frag = tid >> 8, rem = tid & 255, l = rem >> 2, g = rem & 3;
            int jl = l & 15, gh = l >> 4;
            float lo, hi;
            if (frag < 4) {
                int n = frag >> 1, s = frag & 1;
                int j = n * 16 + jl;
                int k0 = s * 32 + gh * 8 + 2 * g;
                float s0 = (k0 < 32) ? (1.f / 3.f) : 1.f;
                float s1 = (k0 + 1 < 32) ? (1.f / 3.f) : 1.f;
                lo = W0[k0 * 32 + j] * s0;
                hi = W0[(k0 + 1) * 32 + j] * s1;
            } else if (frag < 8) {
                const float* W = (frag < 6) ? W1 : W2;
                int n = frag & 1;
                int j = n * 16 + jl;
                int k0 = gh * 8 + 2 * g;            // even k'
                lo = W[(k0 >> 1) * 32 + j];          // orig k = k'/2
                hi = W[((k0 >> 1) + 16) * 32 + j];   // orig k = k'/2+16
            } else {
                int j = jl;
                int k0 = gh * 8 + 2 * g;
                lo = (j < 4) ? W3[(k0 >> 1) * 4 + j] : 0.f;
                hi = (j < 4) ? W3[((k0 >> 1) + 16) * 4 + j] : 0.f;
            }
            wfrag[tid] = packh(lo, hi);
        } else if (tid < 2416) {
            int u = tid - 2304; int ly = u >> 4, j = u & 15;
            float v = 0.f;
            if (ly == 0) v = b0[j];
            else if (ly == 1) v = b0[16 + j];
            else if (ly == 2) v = b1[j];
            else if (ly == 3) v = b1[16 + j];
            else if (ly == 4) v = b2[j];
            else if (ly == 5) v = b2[16 + j];
            else v = (j < 4) ? b3[j] : 0.f;
            bb[u] = v;
        }
    }
}

// ---------------------------------------------------------------------------
// scan (4096 bins, 1 block)
// ---------------------------------------------------------------------------
__global__ __launch_bounds__(256) void scan_k(const unsigned* __restrict__ hist,
                                              unsigned* __restrict__ ofs)
{
    __shared__ unsigned part[256];
    int t = threadIdx.x;
    unsigned loc[16], s = 0;
#pragma unroll
    for (int i = 0; i < 16; ++i) { loc[i] = s; s += hist[t * 16 + i]; }
    part[t] = s;
    __syncthreads();
    for (int d = 1; d < 256; d <<= 1) {
        unsigned v = (t >= d) ? part[t - d] : 0u;
        __syncthreads();
        part[t] += v;
        __syncthreads();
    }
    unsigned base = (t == 0) ? 0u : part[t - 1];
#pragma unroll
    for (int i = 0; i < 16; ++i) ofs[t * 16 + i] = base + loc[i];
}

// ---------------------------------------------------------------------------
// scatter: LDS rank + one global reservation per (block,bin)
// ---------------------------------------------------------------------------
__global__ __launch_bounds__(256) void scatter_k(const float* __restrict__ coords,
                                                 unsigned* __restrict__ ofs,
                                                 float4* __restrict__ sorted)
{
    __shared__ unsigned lcnt[NBIN];
    __shared__ unsigned lbase[NBIN];
    int t = threadIdx.x;
#pragma unroll
    for (int i = 0; i < NBIN / 256; ++i) lcnt[i * 256 + t] = 0;
    __syncthreads();

    int base = blockIdx.x * (PXPT * 256);
    uint sav[PXPT];
#pragma unroll
    for (int i = 0; i < PXPT; ++i) {
        int px = base + i * 256 + t;
        float cx = coords[(size_t)px * 3 + 0];
        float cy = coords[(size_t)px * 3 + 1];
        float cz = coords[(size_t)px * 3 + 2];
        unsigned bn = bin_of(cx, cy, cz);
        unsigned r  = atomicAdd(&lcnt[bn], 1u);
        sav[i] = (bn << 16) | r;
    }
    __syncthreads();
#pragma unroll
    for (int i = 0; i < NBIN / 256; ++i) {
        uint v = lcnt[i * 256 + t];
        lbase[i * 256 + t] = v ? atomicAdd(&ofs[i * 256 + t], v) : 0u;
    }
    __syncthreads();

#pragma unroll
    for (int i = 0; i < PXPT; ++i) {
        int px = base + i * 256 + t;
        float cx = coords[(size_t)px * 3 + 0];
        float cy = coords[(size_t)px * 3 + 1];
        float cz = coords[(size_t)px * 3 + 2];
        unsigned bn = sav[i] >> 16, r = sav[i] & 0xffffu;
        sorted[lbase[bn] + r] = make_float4(cx, cy, cz, __uint_as_float((uint)px));
    }
}

// ---------------------------------------------------------------------------
// Bilinear corner math (align_corners=True, border padding)
// ---------------------------------------------------------------------------
__device__ __forceinline__ void corners(float gx, float gy,
                                        int& i00, int& i01, int& i10, int& i11,
                                        float& wnw, float& wne, float& wsw, float& wse)
{
    float ix = (gx + 1.f) * 0.5f * 511.f;
    float iy = (gy + 1.f) * 0.5f * 511.f;
    float fx = floorf(ix), fy = floorf(iy);
    float tx = ix - fx, ty = iy - fy;
    int x0 = (int)fx, y0 = (int)fy;
    int x1 = min(max(x0 + 1, 0), 511);
    int y1 = min(max(y0 + 1, 0), 511);
    x0 = min(max(x0, 0), 511);
    y0 = min(max(y0, 0), 511);
    i00 = y0 * 512 + x0;
    i01 = y0 * 512 + x1;
    i10 = y1 * 512 + x0;
    i11 = y1 * 512 + x1;
    wnw = (1.f - tx) * (1.f - ty);
    wne = tx * (1.f - ty);
    wsw = (1.f - tx) * ty;
    wse = tx * ty;
}

__device__ __forceinline__ void sample_tp_h(const half_t* __restrict__ pl,
                                            float gx, float gy, half8* __restrict__ acc)
{
    int i00, i01, i10, i11;
    float wnw, wne, wsw, wse;
    corners(gx, gy, i00, i01, i10, i11, wnw, wne, wsw, wse);
    const half8* __restrict__ p00 = (const half8*)(pl + (size_t)i00 * 32);
    const half8* __restrict__ p01 = (const half8*)(pl + (size_t)i01 * 32);
    const half8* __restrict__ p10 = (const half8*)(pl + (size_t)i10 * 32);
    const half8* __restrict__ p11 = (const half8*)(pl + (size_t)i11 * 32);
    half8 W00 = splat8(wnw), W01 = splat8(wne), W10 = splat8(wsw), W11 = splat8(wse);
#pragma unroll
    for (int v = 0; v < 4; ++v) {
        half8 a = p00[v], bq = p01[v], c = p10[v], d = p11[v];
        acc[v] = acc[v] + a * W00 + bq * W01 + c * W10 + d * W11;
    }
}

// ---------------------------------------------------------------------------
// Main decoder: per-lane sample+posenc, per-wave MFMA MLP via wave-private LDS
// ---------------------------------------------------------------------------
__global__ __launch_bounds__(256) void decoder_mfma_k(
    const half_t* __restrict__ tp, const float4* __restrict__ sorted,
    const float* __restrict__ gauss, const uint* __restrict__ wfrag,
    const float* __restrict__ bb, float* __restrict__ out)
{
    __shared__ __align__(16) char lds[4][8192];
    const int t  = threadIdx.x;
    const int l  = t & 63;
    const int wv = t >> 6;
    char* base = lds[wv];
    const int jl = l & 15, gh = l >> 4;

    int b   = blockIdx.x;
    int swz = (b & 7) * 512 + (b >> 3);       // XCD-chunked Morton ranges
    int j   = (swz * 4 + wv) * 64 + l;

    float4 s = sorted[j];
    int gpix = (int)__float_as_uint(s.w);
    float cx = s.x, cy = s.y, cz = s.z;

    // ---- sampling: feats 0..31 as fp16 (3-plane sum; 1/3 folded into W0) ----
    half8 acc[4] = {};
    sample_tp_h(tp,                        cx, cy, acc);
    sample_tp_h(tp + (size_t)HW_ * 32,     cx, cz, acc);
    sample_tp_h(tp + (size_t)2 * HW_ * 32, cy, cz, acc);

    // ---- weight fragments + biases (latency hides under posenc) ----
    half8 wf[9];
#pragma unroll
    for (int f = 0; f < 9; ++f) {
        uint4 u = *(const uint4*)(wfrag + f * 256 + l * 4);
        wf[f] = __builtin_bit_cast(half8, u);
    }
    float bL0a = bb[jl],      bL0b = bb[16 + jl];
    float bL1a = bb[32 + jl], bL1b = bb[48 + jl];
    float bL2a = bb[64 + jl], bL2b = bb[80 + jl];
    float bL3  = bb[96 + jl];

    // ---- positional encoding: feats 32..63 ----
    const float TWO_PI = 6.283185307179586f;
    float px = cx * TWO_PI, py = cy * TWO_PI, pz = cz * TWO_PI;
    float sn[16], cs[16];
#pragma unroll
    for (int c = 0; c < 16; ++c) {
        float pr = px * gauss[c] + py * gauss[16 + c] + pz * gauss[32 + c];
        sn[c] = __sinf(pr);
        cs[c] = __cosf(pr);
    }
    half8 pc[4];
#pragma unroll
    for (int i = 0; i < 8; ++i) {
        pc[0][i] = (half_t)sn[i];     pc[1][i] = (half_t)sn[8 + i];
        pc[2][i] = (half_t)cs[i];     pc[3][i] = (half_t)cs[8 + i];
    }

    // ---- stage act0[pix=l][64 feats] as 8 chunk-swizzled 16B chunks ----
#pragma unroll
    for (int g = 0; g < 4; ++g)
        *(half8*)(base + (l << 7) + ((g ^ (l & 7)) << 4)) = acc[g];
#pragma unroll
    for (int g = 0; g < 4; ++g)
        *(half8*)(base + (l << 7) + (((g + 4) ^ (l & 7)) << 4)) = pc[g];

    // ---- Layer 0: 64 -> 32 (mfma), write act2[pix][16 pair-slots] ----
#pragma unroll
    for (int m = 0; m < 4; ++m) {
        int p = m * 16 + jl;
        half8 a0 = *(const half8*)(base + (p << 7) + (((0 + gh) ^ (p & 7)) << 4));
        half8 a1 = *(const half8*)(base + (p << 7) + (((4 + gh) ^ (p & 7)) << 4));
        f32x4 c0 = {bL0a, bL0a, bL0a, bL0a};
        f32x4 c1 = {bL0b, bL0b, bL0b, bL0b};
        c0 = __builtin_amdgcn_mfma_f32_16x16x32_f16(a0, wf[0], c0, 0, 0, 0);
        c0 = __builtin_amdgcn_mfma_f32_16x16x32_f16(a1, wf[1], c0, 0, 0, 0);
        c1 = __builtin_amdgcn_mfma_f32_16x16x32_f16(a0, wf[2], c1, 0, 0, 0);
        c1 = __builtin_amdgcn_mfma_f32_16x16x32_f16(a1, wf[3], c1, 0, 0, 0);
#pragma unroll
        for (int r = 0; r < 4; ++r) {
            float f0 = c0[r]; f0 = f0 >= 0.f ? f0 : 0.01f * f0;
            float f1 = c1[r]; f1 = f1 >= 0.f ? f1 : 0.01f * f1;
            int q = m * 16 + gh * 4 + r;
            int G = (q ^ (q >> 2)) & 3;
            *(uint*)(base + (q << 6) + ((jl ^ (G << 2)) << 2)) = pkrtz_u32(f0, f1);
        }
    }

    // ---- Layer 1: 32 -> 32 ----
#pragma unroll
    for (int m = 0; m < 4; ++m) {
        int p = m * 16 + jl;
        int G = (p ^ (p >> 2)) & 3;
        half8 a = *(const half8*)(base + (p << 6) + ((gh ^ G) << 4));
        f32x4 c0 = {bL1a, bL1a, bL1a, bL1a};
        f32x4 c1 = {bL1b, bL1b, bL1b, bL1b};
        c0 = __builtin_amdgcn_mfma_f32_16x16x32_f16(a, wf[4], c0, 0, 0, 0);
        c1 = __builtin_amdgcn_mfma_f32_16x16x32_f16(a, wf[5], c1, 0, 0, 0);
#pragma unroll
        for (int r = 0; r < 4; ++r) {
            float f0 = c0[r]; f0 = f0 >= 0.f ? f0 : 0.01f * f0;
            float f1 = c1[r]; f1 = f1 >= 0.f ? f1 : 0.01f * f1;
            int q = m * 16 + gh * 4 + r;
            int Gq = (q ^ (q >> 2)) & 3;
            *(uint*)(base + (q << 6) + ((jl ^ (Gq << 2)) << 2)) = pkrtz_u32(f0, f1);
        }
    }

    // ---- Layer 2: 32 -> 32 ----
#pragma unroll
    for (int m = 0; m < 4; ++m) {
        int p = m * 16 + jl;
        int G = (p ^ (p >> 2)) & 3;
        half8 a = *(const half8*)(base + (p << 6) + ((gh ^ G) << 4));
        f32x4 c0 = {bL2a, bL2a, bL2a, bL2a};
        f32x4 c1 = {bL2b, bL2b, bL2b, bL2b};
        c0 = __builtin_amdgcn_mfma_f32_16x16x32_f16(a, wf[6], c0, 0, 0, 0);
        c1 = __builtin_amdgcn_mfma_f32_16x16x32_f16(a, wf[7], c1, 0, 0, 0);
#pragma unroll
        for (int r = 0; r < 4; ++r) {
            float f0 = c0[r]; f0 = f0 >= 0.f ? f0 : 0.01f * f0;
            float f1 = c1[r]; f1 = f1 >= 0.f ? f1 : 0.01f * f1;
            int q = m * 16 + gh * 4 + r;
            int Gq = (q ^ (q >> 2)) & 3;
            *(uint*)(base + (q << 6) + ((jl ^ (Gq << 2)) << 2)) = pkrtz_u32(f0, f1);
        }
    }

    // ---- Layer 3: 32 -> 4 (padded to 16), transpose out via LDS ----
#pragma unroll
    for (int m = 0; m < 4; ++m) {
        int p = m * 16 + jl;
        int G = (p ^ (p >> 2)) & 3;
        half8 a = *(const half8*)(base + (p << 6) + ((gh ^ G) << 4));
        f32x4 c = {bL3, bL3, bL3, bL3};
        c = __builtin_amdgcn_mfma_f32_16x16x32_f16(a, wf[8], c, 0, 0, 0);
        if (jl < 4) {
#pragma unroll
            for (int r = 0; r < 4; ++r) {
                int q = m * 16 + gh * 4 + r;
                *(float*)(base + 4096 + (q << 4) + (jl << 2)) = c[r];
            }
        }
    }

    f32x4 o = *(const f32x4*)(base + 4096 + (l << 4));
    *(f32x4*)(out + (size_t)gpix * 4) = o;
}

// ---------------------------------------------------------------------------
// Fallback scalar decoder (small workspace) — correctness path only
// ---------------------------------------------------------------------------
__device__ __forceinline__ void sample_dir(const float* __restrict__ pl,
                                           float gx, float gy, float* __restrict__ acc)
{
    int i00, i01, i10, i11;
    float wnw, wne, wsw, wse;
    corners(gx, gy, i00, i01, i10, i11, wnw, wne, wsw, wse);
#pragma unroll
    for (int c = 0; c < 32; ++c) {
        const float* __restrict__ bq = pl + (size_t)c * HW_;
        acc[c] += wnw * bq[i00] + wne * bq[i01] + wsw * bq[i10] + wse * bq[i11];
    }
}

__global__ __launch_bounds__(256) void decoder_fb_k(
    const float* __restrict__ xy, const float* __restrict__ xz,
    const float* __restrict__ yz,
    const float* __restrict__ coords, const float* __restrict__ gauss,
    const float* __restrict__ W0, const float* __restrict__ b0,
    const float* __restrict__ W1, const float* __restrict__ b1,
    const float* __restrict__ W2, const float* __restrict__ b2,
    const float* __restrict__ W3, const float* __restrict__ b3,
    float* __restrict__ out)
{
    int pix = blockIdx.x * 256 + threadIdx.x;
    float cx = coords[(size_t)pix * 3 + 0];
    float cy = coords[(size_t)pix * 3 + 1];
    float cz = coords[(size_t)pix * 3 + 2];

    float act[64];
#pragma unroll
    for (int i = 0; i < 32; ++i) act[i] = 0.f;
    sample_dir(xy, cx, cy, act);
    sample_dir(xz, cx, cz, act);
    sample_dir(yz, cy, cz, act);
#pragma unroll
    for (int i = 0; i < 32; ++i) act[i] *= (1.f / 3.f);

    const float TWO_PI = 6.283185307179586f;
    float px = cx * TWO_PI, py = cy * TWO_PI, pz = cz * TWO_PI;
#pragma unroll
    for (int c = 0; c < 16; ++c) {
        float pr = px * gauss[c] + py * gauss[16 + c] + pz * gauss[32 + c];
        act[32 + c] = __sinf(pr);
        act[48 + c] = __cosf(pr);
    }

    float h[32];
#pragma unroll
    for (int jj = 0; jj < 32; ++jj) h[jj] = b0[jj];
#pragma unroll
    for (int k = 0; k < 64; ++k) {
        float a = act[k];
#pragma unroll
        for (int jj = 0; jj < 32; ++jj) h[jj] = fmaf(a, W0[k * 32 + jj], h[jj]);
    }
#pragma unroll
    for (int jj = 0; jj < 32; ++jj) act[jj] = h[jj] >= 0.f ? h[jj] : 0.01f * h[jj];
#pragma unroll
    for (int jj = 0; jj < 32; ++jj) h[jj] = b1[jj];
#pragma unroll
    for (int k = 0; k < 32; ++k) {
        float a = act[k];
#pragma unroll
        for (int jj = 0; jj < 32; ++jj) h[jj] = fmaf(a, W1[k * 32 + jj], h[jj]);
    }
#pragma unroll
    for (int jj = 0; jj < 32; ++jj) act[jj] = h[jj] >= 0.f ? h[jj] : 0.01f * h[jj];
#pragma unroll
    for (int jj = 0; jj < 32; ++jj) h[jj] = b2[jj];
#pragma unroll
    for (int k = 0; k < 32; ++k) {
        float a = act[k];
#pragma unroll
        for (int jj = 0; jj < 32; ++jj) h[jj] = fmaf(a, W2[k * 32 + jj], h[jj]);
    }
#pragma unroll
    for (int jj = 0; jj < 32; ++jj) act[jj] = h[jj] >= 0.f ? h[jj] : 0.01f * h[jj];
    float o[4];
#pragma unroll
    for (int jj = 0; jj < 4; ++jj) o[jj] = b3[jj];
#pragma unroll
    for (int k = 0; k < 32; ++k) {
        float a = act[k];
#pragma unroll
        for (int jj = 0; jj < 4; ++jj) o[jj] = fmaf(a, W3[k * 4 + jj], o[jj]);
    }
    *(float4*)(out + (size_t)pix * 4) = make_float4(o[0], o[1], o[2], o[3]);
}

// ---------------------------------------------------------------------------
extern "C" void kernel_launch(void* const* d_in, const int* in_sizes, int n_in,
                              void* d_out, int out_size, void* d_ws, size_t ws_size,
                              hipStream_t stream)
{
    const float* xy     = (const float*)d_in[0];
    const float* xz     = (const float*)d_in[1];
    const float* yz     = (const float*)d_in[2];
    const float* coords = (const float*)d_in[3];
    const float* gauss  = (const float*)d_in[4];
    const float* W0     = (const float*)d_in[5];
    const float* b0     = (const float*)d_in[6];
    const float* W1     = (const float*)d_in[7];
    const float* b1     = (const float*)d_in[8];
    const float* W2     = (const float*)d_in[9];
    const float* b2     = (const float*)d_in[10];
    const float* W3     = (const float*)d_in[11];
    const float* b3     = (const float*)d_in[12];
    float* out = (float*)d_out;

    const size_t plane_bytes = (size_t)3 * HW_ * 32 * sizeof(half_t);   // 48 MB
    const size_t hist_off    = plane_bytes;
    const size_t ofs_off     = hist_off + NBIN * 4;                      // 16 KB
    const size_t wfrag_off   = ofs_off + NBIN * 4;
    const size_t bb_off      = wfrag_off + 12288;                        // 2304*4 padded
    const size_t sorted_off  = bb_off + 4096;
    const size_t need_sorted = sorted_off + (size_t)NPIX * sizeof(float4);
    const int npix_blocks    = NPIX / 256;                               // 4096

    if (ws_size >= need_sorted) {
        half_t*   tp     = (half_t*)d_ws;
        unsigned* hist   = (unsigned*)((char*)d_ws + hist_off);
        unsigned* ofs    = (unsigned*)((char*)d_ws + ofs_off);
        uint*     wfrag  = (uint*)((char*)d_ws + wfrag_off);
        float*    bb     = (float*)((char*)d_ws + bb_off);
        float4*   sorted = (float4*)((char*)d_ws + sorted_off);

        (void)hipMemsetAsync(hist, 0, NBIN * 4, stream);
        k1_merged<<<12288 + SORT_BLOCKS + 10, 256, 0, stream>>>(
            xy, xz, yz, tp, coords, hist,
            W0, W1, W2, W3, b0, b1, b2, b3, wfrag, bb);
        scan_k<<<1, 256, 0, stream>>>(hist, ofs);
        scatter_k<<<SORT_BLOCKS, 256, 0, stream>>>(coords, ofs, sorted);
        decoder_mfma_k<<<npix_blocks, 256, 0, stream>>>(
            tp, sorted, gauss, wfrag, bb, out);
    } else {
        decoder_fb_k<<<npix_blocks, 256, 0, stream>>>(
            xy, xz, yz, coords, gauss,
            W0, b0, W1, b1, W2, b2, W3, b3, out);
    }
}